// Round 1
// baseline (8405.984 us; speedup 1.0000x reference)
//
#include <hip/hip_runtime.h>
#include <hip/hip_bf16.h>

// Decoder: attention is step-invariant => ctx precomputed once. Persistent
// kernel runs the 512-step GRU recurrence across 256 WGs (4 row-groups x 64
// col-groups), weights pinned in registers.
// R5: flag barriers ELIMINATED. All cross-WG exchange (e2, h, psumB, psumO)
// is value-polled: buffers are parity double-buffered, producers store
// guaranteed-nonzero u32 granules, consumers burst-load + spin until every
// granule is nonzero (the successful burst IS the staged data -> 1 L3 round
// trip per exchange instead of flag-RT + data-RT, and no producer-side
// vmcnt-drain-before-flag). Owner threads zero their own words at a point
// provably after all consumers finished:
//   - poll-success proves ALL producers posted (every word nonzero)
//   - a producer's posting store is control-dependent on its own prior
//     poll-success (stores are non-speculative), so posting-observed implies
//     its earlier consumption finished and its earlier zero-stores (drained
//     by an intervening __syncthreads vmcnt(0)) are visible.
// Zero schedule: phase A (after e2-poll): PO[par^1]. phase B (after h-poll):
// EB[par], HB[par], PB[par]. Rewrites of zeroed words are by the SAME thread,
// so zero->fresh is program-ordered; consumers can only observe 0 or fresh.

#define HH 1024
#define BB 64
#define LL 512
#define VV 1024

typedef short bf16x8 __attribute__((ext_vector_type(8)));
typedef float f32x4 __attribute__((ext_vector_type(4)));

__device__ __forceinline__ short f2bf(float x) {
  union { float f; unsigned u; } a; a.f = x;
  unsigned r = (a.u + 0x7FFF + ((a.u >> 16) & 1)) >> 16;
  return (short)r;
}

// ---- coherent (cross-XCD, L3-point) access helpers ----
__device__ __forceinline__ unsigned long long ld64c(const void* p) {
  return __hip_atomic_load((const unsigned long long*)p, __ATOMIC_RELAXED, __HIP_MEMORY_SCOPE_AGENT);
}
__device__ __forceinline__ void st32c(void* p, unsigned v) {
  __hip_atomic_store((unsigned*)p, v, __ATOMIC_RELAXED, __HIP_MEMORY_SCOPE_AGENT);
}
__device__ __forceinline__ void stfc(float* p, float v) {
  union { float f; unsigned u; } a; a.f = v;
  st32c(p, a.u);
}

// ---------------- workspace layout (bytes) ----------------
// ES/A are precompute scratch, reused as EB1/HB1 after K_ctx (K_init runs
// after the precompute chain and re-initializes them).
static constexpr size_t OFF_VE    = 0;                       // 1024 f32
static constexpr size_t OFF_ES    = 4096;                    // 64*512 f32  -> EB1
static constexpr size_t OFF_A     = OFF_ES    + 131072;      // 64*512 f32  -> HB1
static constexpr size_t OFF_CTX   = OFF_A     + 131072;      // 64*1024 f32
static constexpr size_t OFF_GICTX = OFF_CTX   + 262144;      // 64*3072 f32
static constexpr size_t OFF_OC    = OFF_GICTX + 786432;      // 64*1024 f32
static constexpr size_t OFF_PB    = OFF_OC    + 262144;      // 2 x 4096 f32 (parity)
static constexpr size_t OFF_PO    = OFF_PB    + 32768;       // 2 x 4096 f32 (parity)
static constexpr size_t OFF_E2    = OFF_PO    + 32768;       // 64*1024 bf16 (EB0)
static constexpr size_t OFF_HB    = OFF_E2    + 131072;      // 64*1024 bf16 (HB0)
static constexpr size_t OFF_PACKW = OFF_HB    + 131072;      // 18 MB packed weights

// ---------------- precompute kernels ----------------

__global__ void K_init(const float* __restrict__ hidden, const float* __restrict__ dec0,
                       unsigned* __restrict__ hb0, unsigned* __restrict__ hb1,
                       unsigned* __restrict__ e20, unsigned* __restrict__ e21,
                       float* __restrict__ pb, float* __restrict__ po) {
  int tid = blockIdx.x * 256 + threadIdx.x;  // grid 128 -> 32768 threads
  {
    float h0 = hidden[2 * tid], h1 = hidden[2 * tid + 1];
    unsigned ph = (unsigned)(unsigned short)f2bf(h0) | ((unsigned)(unsigned short)f2bf(h1) << 16);
    if (ph == 0u) ph = 1u;               // nonzero guard (value-poll protocol)
    hb0[tid] = ph; hb1[tid] = 0u;
    float d0 = dec0[2 * tid], d1 = dec0[2 * tid + 1];
    unsigned pe = (unsigned)(unsigned short)f2bf(d0) | ((unsigned)(unsigned short)f2bf(d1) << 16);
    if (pe == 0u) pe = 1u;
    e20[tid] = pe; e21[tid] = 0u;
  }
  if (tid < 8192) { pb[tid] = 0.f; po[tid] = 0.f; }
}

__global__ void K_ve(const float* __restrict__ Wa, const float* __restrict__ v, float* __restrict__ ve) {
  int i = blockIdx.x * 64 + threadIdx.x;  // 1024 threads
  float acc = 0.f;
  for (int k = 0; k < HH; ++k) acc += Wa[(size_t)k * 2048 + 1024 + i] * v[k];
  ve[i] = acc;
}

__global__ void K_escore(const float* __restrict__ enc, const float* __restrict__ ve, float* __restrict__ es) {
  int bid = blockIdx.x;           // 0..32767 = l*64+b
  int lane = threadIdx.x;         // 64
  const float* row = enc + (size_t)bid * HH;
  float acc = 0.f;
  #pragma unroll
  for (int i = 0; i < 16; ++i) { int k = lane + 64 * i; acc += row[k] * ve[k]; }
  for (int m = 1; m < 64; m <<= 1) acc += __shfl_xor(acc, m);
  if (lane == 0) { int l = bid >> 6, b = bid & 63; es[b * LL + l] = acc; }
}

__global__ void K_asm(const float* __restrict__ es, float* __restrict__ a) {
  __shared__ float red[256];
  int b = blockIdx.x, tid = threadIdx.x;
  float e0 = es[b * LL + tid], e1 = es[b * LL + 256 + tid];
  red[tid] = fmaxf(e0, e1);
  __syncthreads();
  for (int s = 128; s > 0; s >>= 1) { if (tid < s) red[tid] = fmaxf(red[tid], red[tid + s]); __syncthreads(); }
  float M = red[0];
  __syncthreads();
  float x0 = expf(e0 - M), x1 = expf(e1 - M);
  red[tid] = x0 + x1;
  __syncthreads();
  for (int s = 128; s > 0; s >>= 1) { if (tid < s) red[tid] += red[tid + s]; __syncthreads(); }
  float S = red[0];
  a[b * LL + tid] = x0 / S;
  a[b * LL + 256 + tid] = x1 / S;
}

__global__ void K_ctx(const float* __restrict__ enc, const float* __restrict__ a, float* __restrict__ ctx) {
  int b = blockIdx.x >> 3, hc = blockIdx.x & 7;  // 512 blocks, 128 thr
  int h = hc * 128 + threadIdx.x;
  float acc = 0.f;
  for (int l = 0; l < LL; ++l) acc += a[b * LL + l] * enc[(size_t)(l * BB + b) * HH + h];
  ctx[b * HH + h] = acc;
}

__global__ void K_gictx(const float* __restrict__ ctx, const float* __restrict__ W_ih, const float* __restrict__ b_ih,
                        const float* __restrict__ Wo, const float* __restrict__ bo,
                        float* __restrict__ gictx, float* __restrict__ oc) {
  int c = blockIdx.x;      // 4096 blocks
  int b = threadIdx.x;     // 64 threads
  float acc = 0.f;
  if (c < 3072) {
    for (int k = 0; k < HH; ++k) acc += ctx[b * HH + k] * W_ih[(size_t)c * 2048 + 1024 + k];
    gictx[b * 3072 + c] = acc + b_ih[c];
  } else {
    int c2 = c - 3072;
    for (int k = 0; k < HH; ++k) acc += ctx[b * HH + k] * Wo[(size_t)c2 * 3072 + 2048 + k];
    oc[b * HH + c2] = acc + bo[c2];
  }
}

// Pack weights into MFMA B-fragment layout, bf16.
// tiles per col-group cg (16 cols): 0:gi_r(W1) 1:gi_z 2:gi_n 3:Wo_d 4:gh_r(Whh) 5:gh_z 6:gh_n 7:Wf 8:Wo_h
__global__ void K_pack(const float* __restrict__ W_ih, const float* __restrict__ W_hh,
                       const float* __restrict__ Wo, const float* __restrict__ Wf, short* __restrict__ packW) {
  int tid = blockIdx.x * 64 + threadIdx.x;   // 64*9*32*64 = 1,179,648
  int lane = tid & 63;
  int ks = (tid >> 6) & 31;
  int tile = (tid >> 11) % 9;
  int cg = tid / (9 * 32 * 64);
  int n = lane & 15;
  int k0 = ks * 32 + (lane >> 4) * 8;
  int row = cg * 16 + n;
  const float* src;
  size_t base;
  switch (tile) {
    case 0: base = (size_t)row * 2048;               src = W_ih; break;
    case 1: base = (size_t)(1024 + row) * 2048;      src = W_ih; break;
    case 2: base = (size_t)(2048 + row) * 2048;      src = W_ih; break;
    case 3: base = (size_t)row * 3072 + 1024;        src = Wo;   break;
    case 4: base = (size_t)row * 1024;               src = W_hh; break;
    case 5: base = (size_t)(1024 + row) * 1024;      src = W_hh; break;
    case 6: base = (size_t)(2048 + row) * 1024;      src = W_hh; break;
    case 7: base = (size_t)row * 1024;               src = Wf;   break;
    default: base = (size_t)row * 3072;              src = Wo;   break;
  }
  bf16x8 vv;
  #pragma unroll
  for (int j = 0; j < 8; ++j) vv[j] = f2bf(src[base + k0 + j]);
  ((bf16x8*)packW)[tid] = vv;
}

// ---------------- persistent step kernel ----------------

// Burst-load this wave's 8KB quarter of a 16x1024 bf16 slice (16 u64/lane).
#define QLOADS(srcp)                                                           \
  _Pragma("unroll")                                                            \
  for (int i_ = 0; i_ < 8; ++i_) {                                             \
    int off_ = (wave << 12) + (i_ << 9) + (lane << 3);                         \
    tv[2 * i_]     = ld64c((srcp) + off_);                                     \
    tv[2 * i_ + 1] = ld64c((srcp) + off_ + 4);                                 \
  }

// Every u32 granule must be nonzero (producers guarantee it).
#define QCHECK()                                                               \
  _Pragma("unroll")                                                            \
  for (int i_ = 0; i_ < 16; ++i_)                                              \
    ok &= (int)((unsigned)tv[i_] != 0u) & (int)((unsigned)(tv[i_] >> 32) != 0u);

// Write the quarter to LDS with XOR-swizzle: byte_col ^= ((row&7)<<4).
#define QWRITE(dstp)                                                           \
  _Pragma("unroll")                                                            \
  for (int i_ = 0; i_ < 8; ++i_) {                                             \
    int off_ = (wave << 12) + (i_ << 9) + (lane << 3);                         \
    int r_ = off_ >> 10;                                                       \
    int sw_ = ((off_ & 1023) << 1) ^ ((r_ & 7) << 4);                          \
    union { unsigned long long u[2]; bf16x8 v_; } x_;                          \
    x_.u[0] = tv[2 * i_]; x_.u[1] = tv[2 * i_ + 1];                            \
    *(bf16x8*)&(dstp)[(r_ << 10) + (sw_ >> 1)] = x_.v_;                        \
  }

// MFMA A-fragment read from swizzled LDS slice (conflict-free, 2-way max).
#define LFRAG(buf, ks) \
  (*(const bf16x8*)&(buf)[((llo) << 10) + (((((ks) * 64) + (lhi << 4)) ^ ((llo & 7) << 4)) >> 1)])

__global__ __launch_bounds__(256, 1) void K_step(
    const bf16x8* __restrict__ packW,
    short* __restrict__ e2a, short* __restrict__ e2b,
    short* __restrict__ hba, short* __restrict__ hbb,
    const float* __restrict__ hidden,
    float* __restrict__ psumB, float* __restrict__ psumO,
    const float* __restrict__ gictx, const float* __restrict__ ocbuf,
    const float* __restrict__ b_hh, const float* __restrict__ bfv,
    float* __restrict__ outp) {
  const int wg = blockIdx.x;
  const int rg = wg & 3;      // row group: rows [16rg,16rg+16)
  const int cg = wg >> 2;     // col group: 16 cols of each output tile
  const int tid = threadIdx.x;
  const int wave = tid >> 6;
  const int lane = tid & 63;
  const int lhi = lane >> 4;
  const int llo = lane & 15;

  __shared__ short se2[16 * 1024];    // e2(t) slice, swizzled (32KB)
  __shared__ short sh[16 * 1024];     // h(t)/h(t+1) slice, swizzled (32KB)
  __shared__ float lds_g[6][16][17];  // raw gate accs: gi_r gi_z gi_n gh_r gh_z gh_n
  __shared__ float lds_p[5][16][17];  // phase-B partials [0..3] + savedA2 [4]
  __shared__ float lds_rs[16];        // 1/sum per row (e2 normalization)

  const int wbase = cg * (9 * 32 * 64) + lane;
  const int t0 = wave * 2, t1 = wave * 2 + 1;

  // ---- load step-invariant weights, then FORCE them resident ----
  bf16x8 wA0[32], wA1[32], wB8[8];
  #pragma unroll
  for (int ks = 0; ks < 32; ++ks) {
    wA0[ks] = packW[wbase + (t0 * 32 + ks) * 64];
    wA1[ks] = packW[wbase + (t1 * 32 + ks) * 64];
  }
  #pragma unroll
  for (int i = 0; i < 8; ++i) wB8[i] = packW[wbase + (8 * 32 + wave * 8 + i) * 64];
  #pragma unroll
  for (int ks = 0; ks < 32; ++ks) {
    asm volatile("" : "+v"(wA0[ks]));
    asm volatile("" : "+v"(wA1[ks]));
  }
  #pragma unroll
  for (int i = 0; i < 8; ++i) asm volatile("" : "+v"(wB8[i]));

  // ---- step-invariant per-thread scalars; h carried in-register ----
  const int row = tid >> 4, col = tid & 15;
  const int b_ = rg * 16 + row, j = cg * 16 + col;
  const float c_gr  = gictx[b_ * 3072 + j]        + b_hh[j];
  const float c_gz  = gictx[b_ * 3072 + 1024 + j] + b_hh[1024 + j];
  const float c_gn  = gictx[b_ * 3072 + 2048 + j];
  const float c_ghn = b_hh[2048 + j];
  const float c_oc  = ocbuf[b_ * HH + j];
  float h_reg = hidden[b_ * HH + j];
  const float c_bf  = bfv[cg * 16 + llo];

  // parity slice bases (rg-local, shorts)
  short* es0 = e2a + rg * 16384;
  short* es1 = e2b + rg * 16384;
  short* hs0 = hba + rg * 16384;
  short* hs1 = hbb + rg * 16384;

  // pre-stage h(0) from HB0 (written by K_init; kernel-boundary visible)
  {
    unsigned long long tv[16];
    QLOADS(hs0);
    QWRITE(sh);
  }

  for (int t = 0; t <= LL; ++t) {
    const int par = t & 1;
    const short* ecur = par ? es1 : es0;   // EB[par]  : e2(t)
    short* ecur_m = par ? es1 : es0;
    short* hcur   = par ? hs1 : hs0;       // HB[par]  : h(t)
    short* hnxt   = par ? hs0 : hs1;       // HB[par^1]: h(t+1) dest + phase-B src
    short* enxt   = par ? es0 : es1;       // EB[par^1]: e2(t+1) dest
    const float* PBr = psumB + par * 4096 + rg * 1024;        // consumed this step
    float* PBw = psumB + (par ^ 1) * 4096 + rg * 1024;        // produced this step
    float* POw = psumO + par * 4096 + rg * 1024;              // produced+consumed this step
    float* POz = psumO + (par ^ 1) * 4096 + rg * 1024;        // zeroed this step

    // ================= PHASE A stage: value-poll e2(t) (+ wave0: psumB) ====
    {
      unsigned long long tv[16];
      if (wave == 0) {
        unsigned long long pc[8];
        const float* pbl = PBr + llo * 64 + lhi * 16;
        for (;;) {
          int ok = 1;
          QLOADS(ecur);
          QCHECK();
          if (t >= 1) {
            _Pragma("unroll")
            for (int i_ = 0; i_ < 8; ++i_) pc[i_] = ld64c(pbl + i_ * 2);
            _Pragma("unroll")
            for (int i_ = 0; i_ < 8; ++i_)
              ok &= (int)((unsigned)pc[i_] != 0u) & (int)((unsigned)(pc[i_] >> 32) != 0u);
          }
          if (__all(ok)) break;
          __builtin_amdgcn_s_sleep(2);
        }
        QWRITE(se2);
        float total = 1.0f;
        if (t >= 1) {
          float s = 0.f;
          _Pragma("unroll")
          for (int i_ = 0; i_ < 8; ++i_) {
            union { unsigned long long u; float f[2]; } c; c.u = pc[i_];
            s += c.f[0] + c.f[1];
          }
          s += __shfl_xor(s, 16);
          s += __shfl_xor(s, 32);
          total = s;
        }
        if (lane < 16) lds_rs[lane] = 1.0f / total;
      } else {
        for (;;) {
          int ok = 1;
          QLOADS(ecur);
          QCHECK();
          if (__all(ok)) break;
          __builtin_amdgcn_s_sleep(2);
        }
        QWRITE(se2);
      }
    }
    // zero PO[par^1] (consumed at step t-1; proof: e2(t)-poll success above)
    if (wave == 3 && llo == 0) {
      _Pragma("unroll")
      for (int r = 0; r < 4; ++r) stfc(POz + (lhi * 4 + r) * 64 + cg, 0.f);
    }
    __syncthreads();   // sync1: stage + lds_rs visible; drains PO zeros

    // ================= PHASE A =================
    // waves: 0:{gi_r,gi_z}(A=e2) 1:{gi_n,Wo_d}(A=e2) 2:{gh_r,gh_z}(A=h) 3:{gh_n(A=h), Wf(A=e2)}
    const short* A0 = (wave < 2) ? se2 : sh;
    f32x4 acc0 = {0.f, 0.f, 0.f, 0.f}, acc1 = {0.f, 0.f, 0.f, 0.f};
    #pragma unroll
    for (int ks = 0; ks < 32; ++ks) {
      bf16x8 af0 = LFRAG(A0, ks);
      bf16x8 af1 = (wave == 3) ? LFRAG(se2, ks) : af0;
      acc0 = __builtin_amdgcn_mfma_f32_16x16x32_bf16(af0, wA0[ks], acc0, 0, 0, 0);
      acc1 = __builtin_amdgcn_mfma_f32_16x16x32_bf16(af1, wA1[ks], acc1, 0, 0, 0);
    }

    f32x4 savedA2 = {0.f, 0.f, 0.f, 0.f};
    if (wave == 0) {
      #pragma unroll
      for (int r = 0; r < 4; ++r) { lds_g[0][lhi*4+r][llo] = acc0[r]; lds_g[1][lhi*4+r][llo] = acc1[r]; }
    } else if (wave == 1) {
      #pragma unroll
      for (int r = 0; r < 4; ++r) { lds_g[2][lhi*4+r][llo] = acc0[r]; savedA2[r] = acc1[r]; }
    } else if (wave == 2) {
      #pragma unroll
      for (int r = 0; r < 4; ++r) { lds_g[3][lhi*4+r][llo] = acc0[r]; lds_g[4][lhi*4+r][llo] = acc1[r]; }
    } else {
      #pragma unroll
      for (int r = 0; r < 4; ++r) lds_g[5][lhi*4+r][llo] = acc0[r];
    }
    __syncthreads();   // sync2: lds_g visible; all phase-A LDS reads done

    // wave3: out logits -> eo, psumO partials (guarded-nonzero, value-polled)
    f32x4 eo = {0.f, 0.f, 0.f, 0.f};
    if (wave == 3 && t >= 1) {
      #pragma unroll
      for (int r = 0; r < 4; ++r) eo[r] = expf(acc1[r] * lds_rs[lhi*4+r] + c_bf);
      #pragma unroll
      for (int r = 0; r < 4; ++r) {
        float v_ = eo[r];
        v_ += __shfl_xor(v_, 1, 16); v_ += __shfl_xor(v_, 2, 16);
        v_ += __shfl_xor(v_, 4, 16); v_ += __shfl_xor(v_, 8, 16);
        if (llo == 0) { if (v_ == 0.f) v_ = 1e-30f; stfc(POw + (lhi*4+r) * 64 + cg, v_); }
      }
    }

    // GRU elementwise: thread (row,col) owns h[b_,j]; post h(t+1) (guarded)
    {
      float rsr = lds_rs[row];
      float gr  = lds_g[0][row][col] * rsr + lds_g[3][row][col] + c_gr;
      float gz  = lds_g[1][row][col] * rsr + lds_g[4][row][col] + c_gz;
      float gin = lds_g[2][row][col] * rsr + c_gn;
      float ghn = lds_g[5][row][col] + c_ghn;
      float rr = 1.0f / (1.0f + expf(-gr));
      float zz = 1.0f / (1.0f + expf(-gz));
      float nn = tanhf(gin + rr * ghn);
      float hnew = (1.0f - zz) * nn + zz * h_reg;
      h_reg = hnew;
      unsigned short hv = (unsigned short)f2bf(hnew);
      int other = __shfl_xor((int)hv, 1);
      if ((col & 1) == 0) {
        unsigned pk = (unsigned)hv | ((unsigned)(unsigned short)other << 16);
        if (pk == 0u) pk = 1u;
        st32c((unsigned*)hnxt + (row * 512 + (j >> 1)), pk);
      }
    }

    if (t < LL) {
      // ================= PHASE B =================
      // value-poll h(t+1) (+ wave3: psumO for out(t-1), folded into same loop)
      unsigned long long tv[16];
      if (wave == 3) {
        union { unsigned long long u; float f[2]; } c8[8];
        for (;;) {
          int ok = 1;
          QLOADS(hnxt);
          QCHECK();
          if (t >= 1) {
            _Pragma("unroll")
            for (int r = 0; r < 4; ++r) {
              const float* pp = POw + (lhi * 4 + r) * 64 + llo * 4;
              c8[2*r].u   = ld64c(pp);
              c8[2*r+1].u = ld64c(pp + 2);
            }
            _Pragma("unroll")
            for (int i_ = 0; i_ < 8; ++i_)
              ok &= (int)((unsigned)c8[i_].u != 0u) & (int)((unsigned)(c8[i_].u >> 32) != 0u);
          }
          if (__all(ok)) break;
          __builtin_amdgcn_s_sleep(2);
        }
        QWRITE(sh);
        if (t >= 1) {
          _Pragma("unroll")
          for (int r = 0; r < 4; ++r) {
            float s = c8[2*r].f[0] + c8[2*r].f[1] + c8[2*r+1].f[0] + c8[2*r+1].f[1];
            s += __shfl_xor(s, 1, 16); s += __shfl_xor(s, 2, 16);
            s += __shfl_xor(s, 4, 16); s += __shfl_xor(s, 8, 16);
            int b2 = rg * 16 + lhi * 4 + r;
            outp[(size_t)(t - 1) * BB * VV + (size_t)b2 * VV + cg * 16 + llo] = eo[r] / s;
          }
        }
      } else {
        for (;;) {
          int ok = 1;
          QLOADS(hnxt);
          QCHECK();
          if (__all(ok)) break;
          __builtin_amdgcn_s_sleep(2);
        }
        QWRITE(sh);
      }
      // zero own words of EB[par], HB[par], PB[par]
      // (consumed this step; proof: h(t+1)-poll success above)
      if ((col & 1) == 0) {
        st32c((unsigned*)ecur_m + (row * 512 + (j >> 1)), 0u);
        st32c((unsigned*)hcur   + (row * 512 + (j >> 1)), 0u);
      }
      if (col == 0) stfc(psumB + par * 4096 + rg * 1024 + row * 64 + cg, 0.f);
      __syncthreads();   // sync3: sh staged visible; drains zeros

      f32x4 accB = {0.f, 0.f, 0.f, 0.f};
      #pragma unroll
      for (int i = 0; i < 8; ++i) {
        int ks = wave * 8 + i;
        bf16x8 af = LFRAG(sh, ks);
        accB = __builtin_amdgcn_mfma_f32_16x16x32_bf16(af, wB8[i], accB, 0, 0, 0);
      }
      #pragma unroll
      for (int r = 0; r < 4; ++r) lds_p[wave][lhi*4+r][llo] = accB[r];
      if (wave == 1) {
        #pragma unroll
        for (int r = 0; r < 4; ++r) lds_p[4][lhi*4+r][llo] = savedA2[r];
      }
      __syncthreads();   // sync4: lds_p visible

      // e2(t+1) + psumB (guarded-nonzero posts; no barrier)
      {
        float rsr = lds_rs[row];
        float l2 = lds_p[0][row][col] + lds_p[1][row][col] + lds_p[2][row][col] + lds_p[3][row][col]
                 + lds_p[4][row][col] * rsr + c_oc;
        float ev = expf(l2);
        unsigned short eb = (unsigned short)f2bf(ev);
        int other = __shfl_xor((int)eb, 1);
        if ((col & 1) == 0) {
          unsigned pk = (unsigned)eb | ((unsigned)(unsigned short)other << 16);
          if (pk == 0u) pk = 1u;
          st32c((unsigned*)enxt + (row * 512 + (j >> 1)), pk);
        }
        float sv = ev;
        sv += __shfl_xor(sv, 1, 16); sv += __shfl_xor(sv, 2, 16);
        sv += __shfl_xor(sv, 4, 16); sv += __shfl_xor(sv, 8, 16);
        if (col == 0) { if (sv == 0.f) sv = 1e-30f; stfc(PBw + row * 64 + cg, sv); }
      }
    } else {
      // t == LL: standalone psumO poll + out(LL-1)
      if (wave == 3) {
        union { unsigned long long u; float f[2]; } c8[8];
        for (;;) {
          int ok = 1;
          _Pragma("unroll")
          for (int r = 0; r < 4; ++r) {
            const float* pp = POw + (lhi * 4 + r) * 64 + llo * 4;
            c8[2*r].u   = ld64c(pp);
            c8[2*r+1].u = ld64c(pp + 2);
          }
          _Pragma("unroll")
          for (int i_ = 0; i_ < 8; ++i_)
            ok &= (int)((unsigned)c8[i_].u != 0u) & (int)((unsigned)(c8[i_].u >> 32) != 0u);
          if (__all(ok)) break;
          __builtin_amdgcn_s_sleep(2);
        }
        _Pragma("unroll")
        for (int r = 0; r < 4; ++r) {
          float s = c8[2*r].f[0] + c8[2*r].f[1] + c8[2*r+1].f[0] + c8[2*r+1].f[1];
          s += __shfl_xor(s, 1, 16); s += __shfl_xor(s, 2, 16);
          s += __shfl_xor(s, 4, 16); s += __shfl_xor(s, 8, 16);
          int b2 = rg * 16 + lhi * 4 + r;
          outp[(size_t)(t - 1) * BB * VV + (size_t)b2 * VV + cg * 16 + llo] = eo[r] / s;
        }
      }
    }
  }
}

// ---------------- host launcher ----------------

extern "C" void kernel_launch(void* const* d_in, const int* in_sizes, int n_in,
                              void* d_out, int out_size, void* d_ws, size_t ws_size,
                              hipStream_t stream) {
  (void)in_sizes; (void)n_in; (void)out_size; (void)ws_size;
  const float* enc    = (const float*)d_in[0];
  const float* hidden = (const float*)d_in[1];
  const float* dec0   = (const float*)d_in[2];
  const float* Wa     = (const float*)d_in[3];
  // d_in[4] = ba: unused (softmax shift-invariance)
  const float* v      = (const float*)d_in[5];
  const float* W_ih   = (const float*)d_in[6];
  const float* b_ih   = (const float*)d_in[7];
  const float* W_hh   = (const float*)d_in[8];
  const float* b_hh   = (const float*)d_in[9];
  const float* Wo     = (const float*)d_in[10];
  const float* bo     = (const float*)d_in[11];
  const float* Wf     = (const float*)d_in[12];
  const float* bfv    = (const float*)d_in[13];

  char* ws = (char*)d_ws;
  float* ve    = (float*)(ws + OFF_VE);
  float* es    = (float*)(ws + OFF_ES);
  float* attn  = (float*)(ws + OFF_A);
  float* ctx   = (float*)(ws + OFF_CTX);
  float* gictx = (float*)(ws + OFF_GICTX);
  float* oc    = (float*)(ws + OFF_OC);
  float* psumB = (float*)(ws + OFF_PB);
  float* psumO = (float*)(ws + OFF_PO);
  short* e2a   = (short*)(ws + OFF_E2);   // EB0
  short* e2b   = (short*)(ws + OFF_ES);   // EB1 (reuses es scratch)
  short* hba   = (short*)(ws + OFF_HB);   // HB0
  short* hbb   = (short*)(ws + OFF_A);    // HB1 (reuses attn scratch)
  short* packW = (short*)(ws + OFF_PACKW);

  // precompute chain (uses ES/A scratch), THEN K_init re-purposes ES/A as
  // the parity-1 exchange buffers.
  hipLaunchKernelGGL(K_ve, dim3(16), dim3(64), 0, stream, Wa, v, ve);
  hipLaunchKernelGGL(K_escore, dim3(LL * BB), dim3(64), 0, stream, enc, ve, es);
  hipLaunchKernelGGL(K_asm, dim3(BB), dim3(256), 0, stream, es, attn);
  hipLaunchKernelGGL(K_ctx, dim3(512), dim3(128), 0, stream, enc, attn, ctx);
  hipLaunchKernelGGL(K_gictx, dim3(4096), dim3(64), 0, stream, ctx, W_ih, b_ih, Wo, bo, gictx, oc);
  hipLaunchKernelGGL(K_init, dim3(128), dim3(256), 0, stream, hidden, dec0,
                     (unsigned*)hba, (unsigned*)hbb, (unsigned*)e2a, (unsigned*)e2b, psumB, psumO);
  hipLaunchKernelGGL(K_pack, dim3(64 * 9 * 32), dim3(64), 0, stream, W_ih, W_hh, Wo, Wf, packW);
  hipLaunchKernelGGL(K_step, dim3(256), dim3(256), 0, stream,
                     (const bf16x8*)packW, e2a, e2b, hba, hbb, hidden, psumB, psumO,
                     gictx, oc, b_hh, bfv, (float*)d_out);
}

// Round 2
// 6320.529 us; speedup vs baseline: 1.3299x; 1.3299x over previous
//
#include <hip/hip_runtime.h>
#include <hip/hip_bf16.h>

// Decoder: attention is step-invariant (softmax shift-invariance) => ctx
// precomputed once. Persistent kernel runs the 512-step GRU recurrence.
// R6 = R4 protocol (flag barriers; value-polling of R5 REGRESSED: retry unit
// became an 8KB volley -> ~2x fetch traffic and extra RTs under producer
// stagger) + two serial-path cuts:
//  (a) out(t-1) psumO-gather/reduce/store moved into bar2's poll shadow
//      (psumO(t) was drained at bar1; slots reused only in phase A of t+1,
//      so bar2 shadow is the unique safe hidden slot). Removes ~1 RT/step
//      from the inter-wave critical path.
//  (b) __expf-based sigmoid/tanh/exp on the serial GRU/e2/out path
//      (saturation-safe forms; error << bf16 rounding of h/e2).

#define HH 1024
#define BB 64
#define LL 512
#define VV 1024

typedef short bf16x8 __attribute__((ext_vector_type(8)));
typedef float f32x4 __attribute__((ext_vector_type(4)));

__device__ __forceinline__ short f2bf(float x) {
  union { float f; unsigned u; } a; a.f = x;
  unsigned r = (a.u + 0x7FFF + ((a.u >> 16) & 1)) >> 16;
  return (short)r;
}

__device__ __forceinline__ float fsig(float x) {      // sigmoid, saturation-safe
  return 1.0f / (1.0f + __expf(-x));
}
__device__ __forceinline__ float ftanh(float x) {     // tanh, saturation-safe
  float ex = __expf(2.0f * x);
  return 1.0f - 2.0f / (ex + 1.0f);
}

// ---- coherent (cross-XCD, L3-point) access helpers ----
__device__ __forceinline__ unsigned long long ld64c(const void* p) {
  return __hip_atomic_load((const unsigned long long*)p, __ATOMIC_RELAXED, __HIP_MEMORY_SCOPE_AGENT);
}
__device__ __forceinline__ unsigned ld32c(const void* p) {
  return __hip_atomic_load((const unsigned*)p, __ATOMIC_RELAXED, __HIP_MEMORY_SCOPE_AGENT);
}
__device__ __forceinline__ void st32c(void* p, unsigned v) {
  __hip_atomic_store((unsigned*)p, v, __ATOMIC_RELAXED, __HIP_MEMORY_SCOPE_AGENT);
}
__device__ __forceinline__ void stfc(float* p, float v) {
  union { float f; unsigned u; } a; a.f = v;
  st32c(p, a.u);
}

// ---------------- workspace layout (bytes) ----------------
static constexpr size_t OFF_VE    = 0;                       // 1024 f32
static constexpr size_t OFF_ES    = 4096;                    // 64*512 f32
static constexpr size_t OFF_A     = OFF_ES    + 131072;      // 64*512 f32
static constexpr size_t OFF_CTX   = OFF_A     + 131072;      // 64*1024 f32
static constexpr size_t OFF_GICTX = OFF_CTX   + 262144;      // 64*3072 f32
static constexpr size_t OFF_OC    = OFF_GICTX + 786432;      // 64*1024 f32
static constexpr size_t OFF_FLAGS = OFF_OC    + 262144;      // 256 u32 (pad 4KB)
static constexpr size_t OFF_PSUMB = OFF_FLAGS + 4096;        // 4rg*16row*64cg f32
static constexpr size_t OFF_PSUMO = OFF_PSUMB + 16384;       // 4rg*16row*64cg f32
static constexpr size_t OFF_E2    = OFF_PSUMO + 16384;       // 64*1024 bf16
static constexpr size_t OFF_HB0   = OFF_E2    + 131072;      // 64*1024 bf16
static constexpr size_t OFF_HB1   = OFF_HB0   + 131072;      // (unused)
static constexpr size_t OFF_PACKW = OFF_HB1   + 131072;      // 18 MB packed weights

// ---------------- precompute kernels ----------------

__global__ void K_init(const float* __restrict__ hidden, const float* __restrict__ dec0,
                       short* __restrict__ hb, short* __restrict__ e2,
                       unsigned* __restrict__ flags) {
  int tid = blockIdx.x * 256 + threadIdx.x;  // grid 256 -> 65536 threads
  if (tid < BB * HH) {
    hb[tid] = f2bf(hidden[tid]);
    e2[tid] = f2bf(dec0[tid]);
  }
  if (tid < 256) flags[tid] = 0u;
}

__global__ void K_ve(const float* __restrict__ Wa, const float* __restrict__ v, float* __restrict__ ve) {
  int i = blockIdx.x * 64 + threadIdx.x;  // 1024 threads
  float acc = 0.f;
  for (int k = 0; k < HH; ++k) acc += Wa[(size_t)k * 2048 + 1024 + i] * v[k];
  ve[i] = acc;
}

__global__ void K_escore(const float* __restrict__ enc, const float* __restrict__ ve, float* __restrict__ es) {
  int bid = blockIdx.x;           // 0..32767 = l*64+b
  int lane = threadIdx.x;         // 64
  const float* row = enc + (size_t)bid * HH;
  float acc = 0.f;
  #pragma unroll
  for (int i = 0; i < 16; ++i) { int k = lane + 64 * i; acc += row[k] * ve[k]; }
  for (int m = 1; m < 64; m <<= 1) acc += __shfl_xor(acc, m);
  if (lane == 0) { int l = bid >> 6, b = bid & 63; es[b * LL + l] = acc; }
}

__global__ void K_asm(const float* __restrict__ es, float* __restrict__ a) {
  __shared__ float red[256];
  int b = blockIdx.x, tid = threadIdx.x;
  float e0 = es[b * LL + tid], e1 = es[b * LL + 256 + tid];
  red[tid] = fmaxf(e0, e1);
  __syncthreads();
  for (int s = 128; s > 0; s >>= 1) { if (tid < s) red[tid] = fmaxf(red[tid], red[tid + s]); __syncthreads(); }
  float M = red[0];
  __syncthreads();
  float x0 = expf(e0 - M), x1 = expf(e1 - M);
  red[tid] = x0 + x1;
  __syncthreads();
  for (int s = 128; s > 0; s >>= 1) { if (tid < s) red[tid] += red[tid + s]; __syncthreads(); }
  float S = red[0];
  a[b * LL + tid] = x0 / S;
  a[b * LL + 256 + tid] = x1 / S;
}

__global__ void K_ctx(const float* __restrict__ enc, const float* __restrict__ a, float* __restrict__ ctx) {
  int b = blockIdx.x >> 3, hc = blockIdx.x & 7;  // 512 blocks, 128 thr
  int h = hc * 128 + threadIdx.x;
  float acc = 0.f;
  for (int l = 0; l < LL; ++l) acc += a[b * LL + l] * enc[(size_t)(l * BB + b) * HH + h];
  ctx[b * HH + h] = acc;
}

__global__ void K_gictx(const float* __restrict__ ctx, const float* __restrict__ W_ih, const float* __restrict__ b_ih,
                        const float* __restrict__ Wo, const float* __restrict__ bo,
                        float* __restrict__ gictx, float* __restrict__ oc) {
  int c = blockIdx.x;      // 4096 blocks
  int b = threadIdx.x;     // 64 threads
  float acc = 0.f;
  if (c < 3072) {
    for (int k = 0; k < HH; ++k) acc += ctx[b * HH + k] * W_ih[(size_t)c * 2048 + 1024 + k];
    gictx[b * 3072 + c] = acc + b_ih[c];
  } else {
    int c2 = c - 3072;
    for (int k = 0; k < HH; ++k) acc += ctx[b * HH + k] * Wo[(size_t)c2 * 3072 + 2048 + k];
    oc[b * HH + c2] = acc + bo[c2];
  }
}

// Pack weights into MFMA B-fragment layout, bf16.
// tiles per col-group cg (16 cols): 0:gi_r(W1) 1:gi_z 2:gi_n 3:Wo_d 4:gh_r(Whh) 5:gh_z 6:gh_n 7:Wf 8:Wo_h
__global__ void K_pack(const float* __restrict__ W_ih, const float* __restrict__ W_hh,
                       const float* __restrict__ Wo, const float* __restrict__ Wf, short* __restrict__ packW) {
  int tid = blockIdx.x * 64 + threadIdx.x;   // 64*9*32*64 = 1,179,648
  int lane = tid & 63;
  int ks = (tid >> 6) & 31;
  int tile = (tid >> 11) % 9;
  int cg = tid / (9 * 32 * 64);
  int n = lane & 15;
  int k0 = ks * 32 + (lane >> 4) * 8;
  int row = cg * 16 + n;
  const float* src;
  size_t base;
  switch (tile) {
    case 0: base = (size_t)row * 2048;               src = W_ih; break;
    case 1: base = (size_t)(1024 + row) * 2048;      src = W_ih; break;
    case 2: base = (size_t)(2048 + row) * 2048;      src = W_ih; break;
    case 3: base = (size_t)row * 3072 + 1024;        src = Wo;   break;
    case 4: base = (size_t)row * 1024;               src = W_hh; break;
    case 5: base = (size_t)(1024 + row) * 1024;      src = W_hh; break;
    case 6: base = (size_t)(2048 + row) * 1024;      src = W_hh; break;
    case 7: base = (size_t)row * 1024;               src = Wf;   break;
    default: base = (size_t)row * 3072;              src = Wo;   break;
  }
  bf16x8 vv;
  #pragma unroll
  for (int j = 0; j < 8; ++j) vv[j] = f2bf(src[base + k0 + j]);
  ((bf16x8*)packW)[tid] = vv;
}

// ---------------- persistent step kernel ----------------

// Stage a 16x1024 bf16 slice (32KB, contiguous in global) into LDS with
// XOR-swizzle: byte_col ^= ((row&7)<<4). 8 iters/wave, 16B/lane, pipelined.
#define STAGE_SLICE(dst, srcbase)                                              \
  do {                                                                         \
    unsigned long long tv_[16];                                                \
    _Pragma("unroll")                                                          \
    for (int i_ = 0; i_ < 8; ++i_) {                                           \
      int off_ = (wave << 12) + (i_ << 9) + (lane << 3);                       \
      tv_[2 * i_]     = ld64c((srcbase) + off_);                               \
      tv_[2 * i_ + 1] = ld64c((srcbase) + off_ + 4);                           \
    }                                                                          \
    _Pragma("unroll")                                                          \
    for (int i_ = 0; i_ < 8; ++i_) {                                           \
      int off_ = (wave << 12) + (i_ << 9) + (lane << 3);                       \
      int r_ = off_ >> 10;                                                     \
      int bc_ = (off_ & 1023) << 1;                                            \
      int sw_ = bc_ ^ ((r_ & 7) << 4);                                         \
      union { unsigned long long u[2]; bf16x8 v; } x_;                         \
      x_.u[0] = tv_[2 * i_]; x_.u[1] = tv_[2 * i_ + 1];                        \
      *(bf16x8*)&(dst)[(r_ << 10) + (sw_ >> 1)] = x_.v;                        \
    }                                                                          \
  } while (0)

// MFMA A-fragment read from swizzled LDS slice: lane l -> row llo, k-bytes
// ks*64 + lhi*16, XOR'd by ((row&7)<<4). Conflict-free (2-way max).
#define LFRAG(buf, ks) \
  (*(const bf16x8*)&(buf)[((llo) << 10) + (((((ks) * 64) + (lhi << 4)) ^ ((llo & 7) << 4)) >> 1)])

__global__ __launch_bounds__(256, 1) void K_step(
    const bf16x8* __restrict__ packW,
    short* __restrict__ e2, short* __restrict__ hb,
    const float* __restrict__ hidden,
    float* __restrict__ psumB, float* __restrict__ psumO,
    const float* __restrict__ gictx, const float* __restrict__ ocbuf,
    const float* __restrict__ b_hh, const float* __restrict__ bfv,
    float* __restrict__ outp, unsigned* __restrict__ flags) {
  const int wg = blockIdx.x;
  const int rg = wg & 3;      // row group: rows [16rg,16rg+16)
  const int cg = wg >> 2;     // col group: 16 cols of each output tile
  const int tid = threadIdx.x;
  const int wave = tid >> 6;
  const int lane = tid & 63;
  const int lhi = lane >> 4;
  const int llo = lane & 15;

  __shared__ short se2[16 * 1024];    // e2(t) slice, swizzled (32KB)
  __shared__ short sh[16 * 1024];     // h(t)/h_new slice, swizzled (32KB)
  __shared__ float lds_g[6][16][17];  // raw gate accs: gi_r gi_z gi_n gh_r gh_z gh_n
  __shared__ float lds_p[5][16][17];  // phase-B partials [0..3] + savedA2 [4]
  __shared__ float lds_rs[16];        // 1/sum per row (e2 normalization)

  const int wbase = cg * (9 * 32 * 64) + lane;
  const int t0 = wave * 2, t1 = wave * 2 + 1;

  // ---- load step-invariant weights, then FORCE them resident ----
  bf16x8 wA0[32], wA1[32], wB8[8];
  #pragma unroll
  for (int ks = 0; ks < 32; ++ks) {
    wA0[ks] = packW[wbase + (t0 * 32 + ks) * 64];
    wA1[ks] = packW[wbase + (t1 * 32 + ks) * 64];
  }
  #pragma unroll
  for (int i = 0; i < 8; ++i) wB8[i] = packW[wbase + (8 * 32 + wave * 8 + i) * 64];
  #pragma unroll
  for (int ks = 0; ks < 32; ++ks) {
    asm volatile("" : "+v"(wA0[ks]));
    asm volatile("" : "+v"(wA1[ks]));
  }
  #pragma unroll
  for (int i = 0; i < 8; ++i) asm volatile("" : "+v"(wB8[i]));

  // ---- step-invariant per-thread scalars; h carried in-register ----
  const int row = tid >> 4, col = tid & 15;
  const int b_ = rg * 16 + row, j = cg * 16 + col;
  const float c_gr  = gictx[b_ * 3072 + j]        + b_hh[j];
  const float c_gz  = gictx[b_ * 3072 + 1024 + j] + b_hh[1024 + j];
  const float c_gn  = gictx[b_ * 3072 + 2048 + j];
  const float c_ghn = b_hh[2048 + j];
  const float c_oc  = ocbuf[b_ * HH + j];
  float h_reg = hidden[b_ * HH + j];
  const float c_bf  = bfv[cg * 16 + llo];

  unsigned* myflags = flags + rg * 64;
  const short* e2slice = e2 + rg * 16384;
  short*       hslice  = hb + rg * 16384;

  // pre-stage h(0) into lds (phase-B stage keeps it current afterwards)
  STAGE_SLICE(sh, hslice);

  for (int t = 0; t <= LL; ++t) {
    // ---- stage e2(t); wave0 overlaps the rowsum-partials gather ----
    unsigned long long pc[8];
    if (wave == 0 && t >= 1) {
      const float* pp = psumB + rg * 1024 + llo * 64 + lhi * 16;
      #pragma unroll
      for (int i = 0; i < 8; ++i) pc[i] = ld64c(pp + i * 2);
    }
    STAGE_SLICE(se2, e2slice);
    if (wave == 0) {
      float total = 1.0f;
      if (t >= 1) {
        float s = 0.f;
        #pragma unroll
        for (int i = 0; i < 8; ++i) {
          union { unsigned long long u; float f[2]; } c; c.u = pc[i];
          s += c.f[0] + c.f[1];
        }
        s += __shfl_xor(s, 16);
        s += __shfl_xor(s, 32);
        total = s;
      }
      if (lane < 16) lds_rs[lane] = 1.0f / total;
    }
    __syncthreads();   // stage + lds_rs visible

    // ================= PHASE A =================
    // waves: 0:{gi_r,gi_z}(A=e2) 1:{gi_n,Wo_d}(A=e2) 2:{gh_r,gh_z}(A=h) 3:{gh_n(A=h), Wf(A=e2)}
    const short* A0 = (wave < 2) ? se2 : sh;
    f32x4 acc0 = {0.f, 0.f, 0.f, 0.f}, acc1 = {0.f, 0.f, 0.f, 0.f};
    #pragma unroll
    for (int ks = 0; ks < 32; ++ks) {
      bf16x8 af0 = LFRAG(A0, ks);
      bf16x8 af1 = (wave == 3) ? LFRAG(se2, ks) : af0;
      acc0 = __builtin_amdgcn_mfma_f32_16x16x32_bf16(af0, wA0[ks], acc0, 0, 0, 0);
      acc1 = __builtin_amdgcn_mfma_f32_16x16x32_bf16(af1, wA1[ks], acc1, 0, 0, 0);
    }

    // stash raw accumulators to LDS
    f32x4 savedA2;
    if (wave == 0) {
      #pragma unroll
      for (int r = 0; r < 4; ++r) { lds_g[0][lhi*4+r][llo] = acc0[r]; lds_g[1][lhi*4+r][llo] = acc1[r]; }
    } else if (wave == 1) {
      #pragma unroll
      for (int r = 0; r < 4; ++r) { lds_g[2][lhi*4+r][llo] = acc0[r]; savedA2[r] = acc1[r]; }
    } else if (wave == 2) {
      #pragma unroll
      for (int r = 0; r < 4; ++r) { lds_g[3][lhi*4+r][llo] = acc0[r]; lds_g[4][lhi*4+r][llo] = acc1[r]; }
    } else {
      #pragma unroll
      for (int r = 0; r < 4; ++r) lds_g[5][lhi*4+r][llo] = acc0[r];
    }
    __syncthreads();

    // wave3: out logits -> eo, psumO partials (distinct slots, no atomics)
    f32x4 eo = {0.f, 0.f, 0.f, 0.f};
    if (wave == 3 && t >= 1) {
      #pragma unroll
      for (int r = 0; r < 4; ++r) eo[r] = __expf(acc1[r] * lds_rs[lhi*4+r] + c_bf);
      #pragma unroll
      for (int r = 0; r < 4; ++r) {
        float v_ = eo[r];
        v_ += __shfl_xor(v_, 1, 16); v_ += __shfl_xor(v_, 2, 16);
        v_ += __shfl_xor(v_, 4, 16); v_ += __shfl_xor(v_, 8, 16);
        if (llo == 0) stfc(psumO + rg * 1024 + (lhi*4+r) * 64 + cg, v_);
      }
    }

    // GRU elementwise: thread (row,col) owns h[b_,j]
    {
      float rsr = lds_rs[row];
      float gr  = lds_g[0][row][col] * rsr + lds_g[3][row][col] + c_gr;
      float gz  = lds_g[1][row][col] * rsr + lds_g[4][row][col] + c_gz;
      float gin = lds_g[2][row][col] * rsr + c_gn;
      float ghn = lds_g[5][row][col] + c_ghn;
      float rr = fsig(gr);
      float zz = fsig(gz);
      float nn = ftanh(gin + rr * ghn);
      float hnew = (1.0f - zz) * nn + zz * h_reg;
      h_reg = hnew;
      unsigned short hv = (unsigned short)f2bf(hnew);
      int other = __shfl_xor((int)hv, 1);
      if ((col & 1) == 0) {
        unsigned pk = (unsigned)hv | ((unsigned)(unsigned short)other << 16);
        st32c(hb + b_ * HH + (j & ~1), pk);
      }
    }

    // ---- bar1: h_new + psumO visible (flag barrier, rg-local) ----
    {
      unsigned ep = 2u * (unsigned)t + 1u;
      __syncthreads();                  // drains each wave's stores
      if (tid == 0) st32c(myflags + cg, ep);
      if (wave == 0) {
        unsigned f;
        do { f = ld32c(myflags + lane); } while (__any(f < ep));
      }
      __syncthreads();
    }

    // ================= PHASE B =================
    if (t < LL) {
      STAGE_SLICE(sh, hslice);          // h(t+1) -> lds (also next phase A)
      __syncthreads();
      f32x4 accB = {0.f, 0.f, 0.f, 0.f};
      #pragma unroll
      for (int i = 0; i < 8; ++i) {
        int ks = wave * 8 + i;
        bf16x8 af = LFRAG(sh, ks);
        accB = __builtin_amdgcn_mfma_f32_16x16x32_bf16(af, wB8[i], accB, 0, 0, 0);
      }
      #pragma unroll
      for (int r = 0; r < 4; ++r) lds_p[wave][lhi*4+r][llo] = accB[r];
      if (wave == 1) {
        #pragma unroll
        for (int r = 0; r < 4; ++r) lds_p[4][lhi*4+r][llo] = savedA2[r];
      }
      __syncthreads();
      {
        float rsr = lds_rs[row];
        float l2 = lds_p[0][row][col] + lds_p[1][row][col] + lds_p[2][row][col] + lds_p[3][row][col]
                 + lds_p[4][row][col] * rsr + c_oc;
        float ev = __expf(l2);
        unsigned short eb = (unsigned short)f2bf(ev);
        int other = __shfl_xor((int)eb, 1);
        if ((col & 1) == 0) {
          unsigned pk = (unsigned)eb | ((unsigned)(unsigned short)other << 16);
          st32c(e2 + b_ * HH + (j & ~1), pk);
        }
        float sv = ev;
        sv += __shfl_xor(sv, 1, 16); sv += __shfl_xor(sv, 2, 16);
        sv += __shfl_xor(sv, 4, 16); sv += __shfl_xor(sv, 8, 16);
        if (col == 0) stfc(psumB + rg * 1024 + row * 64 + cg, sv);
      }

      // ---- bar2: e2 + psumB visible; out(t-1) hidden in the poll shadow ----
      {
        unsigned ep = 2u * (unsigned)t + 2u;
        __syncthreads();                 // drains e2 + psumB stores
        if (tid == 0) st32c(myflags + cg, ep);
        // out(t-1): wave3 reduces psumO (posted+drained at bar1) and stores
        // the output row, overlapped with wave0's flag poll. Plain stores,
        // never re-read; drained by the closing __syncthreads.
        if (t >= 1 && wave == 3) {
          #pragma unroll
          for (int r = 0; r < 4; ++r) {
            int prow = lhi * 4 + r;
            const float* pp = psumO + rg * 1024 + prow * 64 + llo * 4;
            union { unsigned long long u; float f[2]; } c0, c1;
            c0.u = ld64c(pp); c1.u = ld64c(pp + 2);
            float s = c0.f[0] + c0.f[1] + c1.f[0] + c1.f[1];
            s += __shfl_xor(s, 1, 16); s += __shfl_xor(s, 2, 16);
            s += __shfl_xor(s, 4, 16); s += __shfl_xor(s, 8, 16);
            int b2 = rg * 16 + prow;
            outp[(size_t)(t - 1) * BB * VV + (size_t)b2 * VV + cg * 16 + llo] = eo[r] / s;
          }
        }
        if (wave == 0) {
          unsigned f;
          do { f = ld32c(myflags + lane); } while (__any(f < ep));
        }
        __syncthreads();
      }
    } else {
      // t == LL: no phase B / bar2 — emit final out(LL-1) directly
      if (wave == 3) {
        #pragma unroll
        for (int r = 0; r < 4; ++r) {
          int prow = lhi * 4 + r;
          const float* pp = psumO + rg * 1024 + prow * 64 + llo * 4;
          union { unsigned long long u; float f[2]; } c0, c1;
          c0.u = ld64c(pp); c1.u = ld64c(pp + 2);
          float s = c0.f[0] + c0.f[1] + c1.f[0] + c1.f[1];
          s += __shfl_xor(s, 1, 16); s += __shfl_xor(s, 2, 16);
          s += __shfl_xor(s, 4, 16); s += __shfl_xor(s, 8, 16);
          int b2 = rg * 16 + prow;
          outp[(size_t)(t - 1) * BB * VV + (size_t)b2 * VV + cg * 16 + llo] = eo[r] / s;
        }
      }
    }
  }
}

// ---------------- host launcher ----------------

extern "C" void kernel_launch(void* const* d_in, const int* in_sizes, int n_in,
                              void* d_out, int out_size, void* d_ws, size_t ws_size,
                              hipStream_t stream) {
  (void)in_sizes; (void)n_in; (void)out_size; (void)ws_size;
  const float* enc    = (const float*)d_in[0];
  const float* hidden = (const float*)d_in[1];
  const float* dec0   = (const float*)d_in[2];
  const float* Wa     = (const float*)d_in[3];
  // d_in[4] = ba: unused (softmax shift-invariance)
  const float* v      = (const float*)d_in[5];
  const float* W_ih   = (const float*)d_in[6];
  const float* b_ih   = (const float*)d_in[7];
  const float* W_hh   = (const float*)d_in[8];
  const float* b_hh   = (const float*)d_in[9];
  const float* Wo     = (const float*)d_in[10];
  const float* bo     = (const float*)d_in[11];
  const float* Wf     = (const float*)d_in[12];
  const float* bfv    = (const float*)d_in[13];

  char* ws = (char*)d_ws;
  float* ve    = (float*)(ws + OFF_VE);
  float* es    = (float*)(ws + OFF_ES);
  float* attn  = (float*)(ws + OFF_A);
  float* ctx   = (float*)(ws + OFF_CTX);
  float* gictx = (float*)(ws + OFF_GICTX);
  float* oc    = (float*)(ws + OFF_OC);
  unsigned* flags = (unsigned*)(ws + OFF_FLAGS);
  float* psumB = (float*)(ws + OFF_PSUMB);
  float* psumO = (float*)(ws + OFF_PSUMO);
  short* e2    = (short*)(ws + OFF_E2);
  short* hb    = (short*)(ws + OFF_HB0);
  short* packW = (short*)(ws + OFF_PACKW);

  hipLaunchKernelGGL(K_init, dim3(256), dim3(256), 0, stream, hidden, dec0, hb, e2, flags);
  hipLaunchKernelGGL(K_ve, dim3(16), dim3(64), 0, stream, Wa, v, ve);
  hipLaunchKernelGGL(K_escore, dim3(LL * BB), dim3(64), 0, stream, enc, ve, es);
  hipLaunchKernelGGL(K_asm, dim3(BB), dim3(256), 0, stream, es, attn);
  hipLaunchKernelGGL(K_ctx, dim3(512), dim3(128), 0, stream, enc, attn, ctx);
  hipLaunchKernelGGL(K_gictx, dim3(4096), dim3(64), 0, stream, ctx, W_ih, b_ih, Wo, bo, gictx, oc);
  hipLaunchKernelGGL(K_pack, dim3(64 * 9 * 32), dim3(64), 0, stream, W_ih, W_hh, Wo, Wf, packW);
  hipLaunchKernelGGL(K_step, dim3(256), dim3(256), 0, stream,
                     (const bf16x8*)packW, e2, hb, hidden, psumB, psumO,
                     gictx, oc, b_hh, bfv, (float*)d_out, flags);
}

// Round 3
// 5316.154 us; speedup vs baseline: 1.5812x; 1.1889x over previous
//
#include <hip/hip_runtime.h>
#include <hip/hip_bf16.h>

// Decoder: attention is step-invariant (softmax shift-invariance) => ctx
// precomputed once. Persistent kernel runs the 512-step GRU recurrence.
// R7 = R6 + flag de-thrash:
//  (a) flags padded to ONE PER 128B LINE (was 64 flags in 2 lines: 32
//      writers/line serializing against 64x64-lane poll traffic = hot-line
//      ping-pong, the suspected hidden ~7us/step). Post is now
//      contention-free; poll is a 64-distinct-line parallel gather.
//  (b) psumB reduce + lds_rs write moved AFTER sync1 (hidden under other
//      waves' phase-A MFMAs; readers only need lds_rs after sync2, and
//      prior-step readers finished before bar2 -> no hazard).
// R6 carried: out(t-1) epilogue in bar2's poll shadow; __expf-based
// sigmoid/tanh/exp on the serial path. R5 lesson: poll cheap, load once
// (value-polling 8KB volleys regressed 2x on retry traffic).

#define HH 1024
#define BB 64
#define LL 512
#define VV 1024

typedef short bf16x8 __attribute__((ext_vector_type(8)));
typedef float f32x4 __attribute__((ext_vector_type(4)));

__device__ __forceinline__ short f2bf(float x) {
  union { float f; unsigned u; } a; a.f = x;
  unsigned r = (a.u + 0x7FFF + ((a.u >> 16) & 1)) >> 16;
  return (short)r;
}

__device__ __forceinline__ float fsig(float x) {      // sigmoid, saturation-safe
  return 1.0f / (1.0f + __expf(-x));
}
__device__ __forceinline__ float ftanh(float x) {     // tanh, saturation-safe
  float ex = __expf(2.0f * x);
  return 1.0f - 2.0f / (ex + 1.0f);
}

// ---- coherent (cross-XCD, L3-point) access helpers ----
__device__ __forceinline__ unsigned long long ld64c(const void* p) {
  return __hip_atomic_load((const unsigned long long*)p, __ATOMIC_RELAXED, __HIP_MEMORY_SCOPE_AGENT);
}
__device__ __forceinline__ unsigned ld32c(const void* p) {
  return __hip_atomic_load((const unsigned*)p, __ATOMIC_RELAXED, __HIP_MEMORY_SCOPE_AGENT);
}
__device__ __forceinline__ void st32c(void* p, unsigned v) {
  __hip_atomic_store((unsigned*)p, v, __ATOMIC_RELAXED, __HIP_MEMORY_SCOPE_AGENT);
}
__device__ __forceinline__ void stfc(float* p, float v) {
  union { float f; unsigned u; } a; a.f = v;
  st32c(p, a.u);
}

// ---------------- workspace layout (bytes) ----------------
// FLAGS: 4 rg * 64 cg * 128B (one line per WG) = 32 KB
static constexpr size_t OFF_VE    = 0;                       // 1024 f32
static constexpr size_t OFF_ES    = 4096;                    // 64*512 f32
static constexpr size_t OFF_A     = OFF_ES    + 131072;      // 64*512 f32
static constexpr size_t OFF_CTX   = OFF_A     + 131072;      // 64*1024 f32
static constexpr size_t OFF_GICTX = OFF_CTX   + 262144;      // 64*3072 f32
static constexpr size_t OFF_OC    = OFF_GICTX + 786432;      // 64*1024 f32
static constexpr size_t OFF_FLAGS = OFF_OC    + 262144;      // 8192 u32 (one/128B)
static constexpr size_t OFF_PSUMB = OFF_FLAGS + 32768;       // 4rg*16row*64cg f32
static constexpr size_t OFF_PSUMO = OFF_PSUMB + 16384;       // 4rg*16row*64cg f32
static constexpr size_t OFF_E2    = OFF_PSUMO + 16384;       // 64*1024 bf16
static constexpr size_t OFF_HB0   = OFF_E2    + 131072;      // 64*1024 bf16
static constexpr size_t OFF_HB1   = OFF_HB0   + 131072;      // (unused)
static constexpr size_t OFF_PACKW = OFF_HB1   + 131072;      // 18 MB packed weights

// ---------------- precompute kernels ----------------

__global__ void K_init(const float* __restrict__ hidden, const float* __restrict__ dec0,
                       short* __restrict__ hb, short* __restrict__ e2,
                       unsigned* __restrict__ flags) {
  int tid = blockIdx.x * 256 + threadIdx.x;  // grid 256 -> 65536 threads
  if (tid < BB * HH) {
    hb[tid] = f2bf(hidden[tid]);
    e2[tid] = f2bf(dec0[tid]);
  }
  if (tid < 8192) flags[tid] = 0u;
}

__global__ void K_ve(const float* __restrict__ Wa, const float* __restrict__ v, float* __restrict__ ve) {
  int i = blockIdx.x * 64 + threadIdx.x;  // 1024 threads
  float acc = 0.f;
  for (int k = 0; k < HH; ++k) acc += Wa[(size_t)k * 2048 + 1024 + i] * v[k];
  ve[i] = acc;
}

__global__ void K_escore(const float* __restrict__ enc, const float* __restrict__ ve, float* __restrict__ es) {
  int bid = blockIdx.x;           // 0..32767 = l*64+b
  int lane = threadIdx.x;         // 64
  const float* row = enc + (size_t)bid * HH;
  float acc = 0.f;
  #pragma unroll
  for (int i = 0; i < 16; ++i) { int k = lane + 64 * i; acc += row[k] * ve[k]; }
  for (int m = 1; m < 64; m <<= 1) acc += __shfl_xor(acc, m);
  if (lane == 0) { int l = bid >> 6, b = bid & 63; es[b * LL + l] = acc; }
}

__global__ void K_asm(const float* __restrict__ es, float* __restrict__ a) {
  __shared__ float red[256];
  int b = blockIdx.x, tid = threadIdx.x;
  float e0 = es[b * LL + tid], e1 = es[b * LL + 256 + tid];
  red[tid] = fmaxf(e0, e1);
  __syncthreads();
  for (int s = 128; s > 0; s >>= 1) { if (tid < s) red[tid] = fmaxf(red[tid], red[tid + s]); __syncthreads(); }
  float M = red[0];
  __syncthreads();
  float x0 = expf(e0 - M), x1 = expf(e1 - M);
  red[tid] = x0 + x1;
  __syncthreads();
  for (int s = 128; s > 0; s >>= 1) { if (tid < s) red[tid] += red[tid + s]; __syncthreads(); }
  float S = red[0];
  a[b * LL + tid] = x0 / S;
  a[b * LL + 256 + tid] = x1 / S;
}

__global__ void K_ctx(const float* __restrict__ enc, const float* __restrict__ a, float* __restrict__ ctx) {
  int b = blockIdx.x >> 3, hc = blockIdx.x & 7;  // 512 blocks, 128 thr
  int h = hc * 128 + threadIdx.x;
  float acc = 0.f;
  for (int l = 0; l < LL; ++l) acc += a[b * LL + l] * enc[(size_t)(l * BB + b) * HH + h];
  ctx[b * HH + h] = acc;
}

__global__ void K_gictx(const float* __restrict__ ctx, const float* __restrict__ W_ih, const float* __restrict__ b_ih,
                        const float* __restrict__ Wo, const float* __restrict__ bo,
                        float* __restrict__ gictx, float* __restrict__ oc) {
  int c = blockIdx.x;      // 4096 blocks
  int b = threadIdx.x;     // 64 threads
  float acc = 0.f;
  if (c < 3072) {
    for (int k = 0; k < HH; ++k) acc += ctx[b * HH + k] * W_ih[(size_t)c * 2048 + 1024 + k];
    gictx[b * 3072 + c] = acc + b_ih[c];
  } else {
    int c2 = c - 3072;
    for (int k = 0; k < HH; ++k) acc += ctx[b * HH + k] * Wo[(size_t)c2 * 3072 + 2048 + k];
    oc[b * HH + c2] = acc + bo[c2];
  }
}

// Pack weights into MFMA B-fragment layout, bf16.
// tiles per col-group cg (16 cols): 0:gi_r(W1) 1:gi_z 2:gi_n 3:Wo_d 4:gh_r(Whh) 5:gh_z 6:gh_n 7:Wf 8:Wo_h
__global__ void K_pack(const float* __restrict__ W_ih, const float* __restrict__ W_hh,
                       const float* __restrict__ Wo, const float* __restrict__ Wf, short* __restrict__ packW) {
  int tid = blockIdx.x * 64 + threadIdx.x;   // 64*9*32*64 = 1,179,648
  int lane = tid & 63;
  int ks = (tid >> 6) & 31;
  int tile = (tid >> 11) % 9;
  int cg = tid / (9 * 32 * 64);
  int n = lane & 15;
  int k0 = ks * 32 + (lane >> 4) * 8;
  int row = cg * 16 + n;
  const float* src;
  size_t base;
  switch (tile) {
    case 0: base = (size_t)row * 2048;               src = W_ih; break;
    case 1: base = (size_t)(1024 + row) * 2048;      src = W_ih; break;
    case 2: base = (size_t)(2048 + row) * 2048;      src = W_ih; break;
    case 3: base = (size_t)row * 3072 + 1024;        src = Wo;   break;
    case 4: base = (size_t)row * 1024;               src = W_hh; break;
    case 5: base = (size_t)(1024 + row) * 1024;      src = W_hh; break;
    case 6: base = (size_t)(2048 + row) * 1024;      src = W_hh; break;
    case 7: base = (size_t)row * 1024;               src = Wf;   break;
    default: base = (size_t)row * 3072;              src = Wo;   break;
  }
  bf16x8 vv;
  #pragma unroll
  for (int j = 0; j < 8; ++j) vv[j] = f2bf(src[base + k0 + j]);
  ((bf16x8*)packW)[tid] = vv;
}

// ---------------- persistent step kernel ----------------

// Stage a 16x1024 bf16 slice (32KB, contiguous in global) into LDS with
// XOR-swizzle: byte_col ^= ((row&7)<<4). 8 iters/wave, 16B/lane, pipelined.
#define STAGE_SLICE(dst, srcbase)                                              \
  do {                                                                         \
    unsigned long long tv_[16];                                                \
    _Pragma("unroll")                                                          \
    for (int i_ = 0; i_ < 8; ++i_) {                                           \
      int off_ = (wave << 12) + (i_ << 9) + (lane << 3);                       \
      tv_[2 * i_]     = ld64c((srcbase) + off_);                               \
      tv_[2 * i_ + 1] = ld64c((srcbase) + off_ + 4);                           \
    }                                                                          \
    _Pragma("unroll")                                                          \
    for (int i_ = 0; i_ < 8; ++i_) {                                           \
      int off_ = (wave << 12) + (i_ << 9) + (lane << 3);                       \
      int r_ = off_ >> 10;                                                     \
      int bc_ = (off_ & 1023) << 1;                                            \
      int sw_ = bc_ ^ ((r_ & 7) << 4);                                         \
      union { unsigned long long u[2]; bf16x8 v; } x_;                         \
      x_.u[0] = tv_[2 * i_]; x_.u[1] = tv_[2 * i_ + 1];                        \
      *(bf16x8*)&(dst)[(r_ << 10) + (sw_ >> 1)] = x_.v;                        \
    }                                                                          \
  } while (0)

// MFMA A-fragment read from swizzled LDS slice: lane l -> row llo, k-bytes
// ks*64 + lhi*16, XOR'd by ((row&7)<<4). Conflict-free (2-way max).
#define LFRAG(buf, ks) \
  (*(const bf16x8*)&(buf)[((llo) << 10) + (((((ks) * 64) + (lhi << 4)) ^ ((llo & 7) << 4)) >> 1)])

__global__ __launch_bounds__(256, 1) void K_step(
    const bf16x8* __restrict__ packW,
    short* __restrict__ e2, short* __restrict__ hb,
    const float* __restrict__ hidden,
    float* __restrict__ psumB, float* __restrict__ psumO,
    const float* __restrict__ gictx, const float* __restrict__ ocbuf,
    const float* __restrict__ b_hh, const float* __restrict__ bfv,
    float* __restrict__ outp, unsigned* __restrict__ flags) {
  const int wg = blockIdx.x;
  const int rg = wg & 3;      // row group: rows [16rg,16rg+16)
  const int cg = wg >> 2;     // col group: 16 cols of each output tile
  const int tid = threadIdx.x;
  const int wave = tid >> 6;
  const int lane = tid & 63;
  const int lhi = lane >> 4;
  const int llo = lane & 15;

  __shared__ short se2[16 * 1024];    // e2(t) slice, swizzled (32KB)
  __shared__ short sh[16 * 1024];     // h(t)/h_new slice, swizzled (32KB)
  __shared__ float lds_g[6][16][17];  // raw gate accs: gi_r gi_z gi_n gh_r gh_z gh_n
  __shared__ float lds_p[5][16][17];  // phase-B partials [0..3] + savedA2 [4]
  __shared__ float lds_rs[16];        // 1/sum per row (e2 normalization)

  const int wbase = cg * (9 * 32 * 64) + lane;
  const int t0 = wave * 2, t1 = wave * 2 + 1;

  // ---- load step-invariant weights, then FORCE them resident ----
  bf16x8 wA0[32], wA1[32], wB8[8];
  #pragma unroll
  for (int ks = 0; ks < 32; ++ks) {
    wA0[ks] = packW[wbase + (t0 * 32 + ks) * 64];
    wA1[ks] = packW[wbase + (t1 * 32 + ks) * 64];
  }
  #pragma unroll
  for (int i = 0; i < 8; ++i) wB8[i] = packW[wbase + (8 * 32 + wave * 8 + i) * 64];
  #pragma unroll
  for (int ks = 0; ks < 32; ++ks) {
    asm volatile("" : "+v"(wA0[ks]));
    asm volatile("" : "+v"(wA1[ks]));
  }
  #pragma unroll
  for (int i = 0; i < 8; ++i) asm volatile("" : "+v"(wB8[i]));

  // ---- step-invariant per-thread scalars; h carried in-register ----
  const int row = tid >> 4, col = tid & 15;
  const int b_ = rg * 16 + row, j = cg * 16 + col;
  const float c_gr  = gictx[b_ * 3072 + j]        + b_hh[j];
  const float c_gz  = gictx[b_ * 3072 + 1024 + j] + b_hh[1024 + j];
  const float c_gn  = gictx[b_ * 3072 + 2048 + j];
  const float c_ghn = b_hh[2048 + j];
  const float c_oc  = ocbuf[b_ * HH + j];
  float h_reg = hidden[b_ * HH + j];
  const float c_bf  = bfv[cg * 16 + llo];

  // one flag per 128B line: flags[(rg*64 + cg) * 32]
  unsigned* myflags = flags + rg * (64 * 32);
  const short* e2slice = e2 + rg * 16384;
  short*       hslice  = hb + rg * 16384;

  // pre-stage h(0) into lds (phase-B stage keeps it current afterwards)
  STAGE_SLICE(sh, hslice);

  for (int t = 0; t <= LL; ++t) {
    // ---- stage e2(t); wave0 issues the rowsum-partials gather first ----
    unsigned long long pc[8];
    if (wave == 0 && t >= 1) {
      const float* pp = psumB + rg * 1024 + llo * 64 + lhi * 16;
      #pragma unroll
      for (int i = 0; i < 8; ++i) pc[i] = ld64c(pp + i * 2);
    }
    STAGE_SLICE(se2, e2slice);
    __syncthreads();   // sync1: stage visible

    // wave0: psumB reduce + lds_rs write AFTER sync1 (hidden under other
    // waves' phase-A MFMAs; readers need lds_rs only after sync2)
    if (wave == 0) {
      float total = 1.0f;
      if (t >= 1) {
        float s = 0.f;
        #pragma unroll
        for (int i = 0; i < 8; ++i) {
          union { unsigned long long u; float f[2]; } c; c.u = pc[i];
          s += c.f[0] + c.f[1];
        }
        s += __shfl_xor(s, 16);
        s += __shfl_xor(s, 32);
        total = s;
      }
      if (lane < 16) lds_rs[lane] = 1.0f / total;
    }

    // ================= PHASE A =================
    // waves: 0:{gi_r,gi_z}(A=e2) 1:{gi_n,Wo_d}(A=e2) 2:{gh_r,gh_z}(A=h) 3:{gh_n(A=h), Wf(A=e2)}
    const short* A0 = (wave < 2) ? se2 : sh;
    f32x4 acc0 = {0.f, 0.f, 0.f, 0.f}, acc1 = {0.f, 0.f, 0.f, 0.f};
    #pragma unroll
    for (int ks = 0; ks < 32; ++ks) {
      bf16x8 af0 = LFRAG(A0, ks);
      bf16x8 af1 = (wave == 3) ? LFRAG(se2, ks) : af0;
      acc0 = __builtin_amdgcn_mfma_f32_16x16x32_bf16(af0, wA0[ks], acc0, 0, 0, 0);
      acc1 = __builtin_amdgcn_mfma_f32_16x16x32_bf16(af1, wA1[ks], acc1, 0, 0, 0);
    }

    // stash raw accumulators to LDS
    f32x4 savedA2;
    if (wave == 0) {
      #pragma unroll
      for (int r = 0; r < 4; ++r) { lds_g[0][lhi*4+r][llo] = acc0[r]; lds_g[1][lhi*4+r][llo] = acc1[r]; }
    } else if (wave == 1) {
      #pragma unroll
      for (int r = 0; r < 4; ++r) { lds_g[2][lhi*4+r][llo] = acc0[r]; savedA2[r] = acc1[r]; }
    } else if (wave == 2) {
      #pragma unroll
      for (int r = 0; r < 4; ++r) { lds_g[3][lhi*4+r][llo] = acc0[r]; lds_g[4][lhi*4+r][llo] = acc1[r]; }
    } else {
      #pragma unroll
      for (int r = 0; r < 4; ++r) lds_g[5][lhi*4+r][llo] = acc0[r];
    }
    __syncthreads();   // sync2: lds_g + lds_rs visible

    // wave3: out logits -> eo, psumO partials (distinct slots, no atomics)
    f32x4 eo = {0.f, 0.f, 0.f, 0.f};
    if (wave == 3 && t >= 1) {
      #pragma unroll
      for (int r = 0; r < 4; ++r) eo[r] = __expf(acc1[r] * lds_rs[lhi*4+r] + c_bf);
      #pragma unroll
      for (int r = 0; r < 4; ++r) {
        float v_ = eo[r];
        v_ += __shfl_xor(v_, 1, 16); v_ += __shfl_xor(v_, 2, 16);
        v_ += __shfl_xor(v_, 4, 16); v_ += __shfl_xor(v_, 8, 16);
        if (llo == 0) stfc(psumO + rg * 1024 + (lhi*4+r) * 64 + cg, v_);
      }
    }

    // GRU elementwise: thread (row,col) owns h[b_,j]
    {
      float rsr = lds_rs[row];
      float gr  = lds_g[0][row][col] * rsr + lds_g[3][row][col] + c_gr;
      float gz  = lds_g[1][row][col] * rsr + lds_g[4][row][col] + c_gz;
      float gin = lds_g[2][row][col] * rsr + c_gn;
      float ghn = lds_g[5][row][col] + c_ghn;
      float rr = fsig(gr);
      float zz = fsig(gz);
      float nn = ftanh(gin + rr * ghn);
      float hnew = (1.0f - zz) * nn + zz * h_reg;
      h_reg = hnew;
      unsigned short hv = (unsigned short)f2bf(hnew);
      int other = __shfl_xor((int)hv, 1);
      if ((col & 1) == 0) {
        unsigned pk = (unsigned)hv | ((unsigned)(unsigned short)other << 16);
        st32c(hb + b_ * HH + (j & ~1), pk);
      }
    }

    // ---- bar1: h_new + psumO visible (flag barrier, rg-local) ----
    {
      unsigned ep = 2u * (unsigned)t + 1u;
      __syncthreads();                  // drains each wave's stores
      if (tid == 0) st32c(myflags + cg * 32, ep);
      if (wave == 0) {
        unsigned f;
        do { f = ld32c(myflags + lane * 32); } while (__any(f < ep));
      }
      __syncthreads();
    }

    // ================= PHASE B =================
    if (t < LL) {
      STAGE_SLICE(sh, hslice);          // h(t+1) -> lds (also next phase A)
      __syncthreads();
      f32x4 accB = {0.f, 0.f, 0.f, 0.f};
      #pragma unroll
      for (int i = 0; i < 8; ++i) {
        int ks = wave * 8 + i;
        bf16x8 af = LFRAG(sh, ks);
        accB = __builtin_amdgcn_mfma_f32_16x16x32_bf16(af, wB8[i], accB, 0, 0, 0);
      }
      #pragma unroll
      for (int r = 0; r < 4; ++r) lds_p[wave][lhi*4+r][llo] = accB[r];
      if (wave == 1) {
        #pragma unroll
        for (int r = 0; r < 4; ++r) lds_p[4][lhi*4+r][llo] = savedA2[r];
      }
      __syncthreads();
      {
        float rsr = lds_rs[row];
        float l2 = lds_p[0][row][col] + lds_p[1][row][col] + lds_p[2][row][col] + lds_p[3][row][col]
                 + lds_p[4][row][col] * rsr + c_oc;
        float ev = __expf(l2);
        unsigned short eb = (unsigned short)f2bf(ev);
        int other = __shfl_xor((int)eb, 1);
        if ((col & 1) == 0) {
          unsigned pk = (unsigned)eb | ((unsigned)(unsigned short)other << 16);
          st32c(e2 + b_ * HH + (j & ~1), pk);
        }
        float sv = ev;
        sv += __shfl_xor(sv, 1, 16); sv += __shfl_xor(sv, 2, 16);
        sv += __shfl_xor(sv, 4, 16); sv += __shfl_xor(sv, 8, 16);
        if (col == 0) stfc(psumB + rg * 1024 + row * 64 + cg, sv);
      }

      // ---- bar2: e2 + psumB visible; out(t-1) hidden in the poll shadow ----
      {
        unsigned ep = 2u * (unsigned)t + 2u;
        __syncthreads();                 // drains e2 + psumB stores
        if (tid == 0) st32c(myflags + cg * 32, ep);
        // out(t-1): wave3 reduces psumO (posted+drained at bar1) and stores
        // the output row, overlapped with wave0's flag poll. Plain stores,
        // never re-read; drained by the closing __syncthreads.
        if (t >= 1 && wave == 3) {
          #pragma unroll
          for (int r = 0; r < 4; ++r) {
            int prow = lhi * 4 + r;
            const float* pp = psumO + rg * 1024 + prow * 64 + llo * 4;
            union { unsigned long long u; float f[2]; } c0, c1;
            c0.u = ld64c(pp); c1.u = ld64c(pp + 2);
            float s = c0.f[0] + c0.f[1] + c1.f[0] + c1.f[1];
            s += __shfl_xor(s, 1, 16); s += __shfl_xor(s, 2, 16);
            s += __shfl_xor(s, 4, 16); s += __shfl_xor(s, 8, 16);
            int b2 = rg * 16 + prow;
            outp[(size_t)(t - 1) * BB * VV + (size_t)b2 * VV + cg * 16 + llo] = eo[r] / s;
          }
        }
        if (wave == 0) {
          unsigned f;
          do { f = ld32c(myflags + lane * 32); } while (__any(f < ep));
        }
        __syncthreads();
      }
    } else {
      // t == LL: no phase B / bar2 — emit final out(LL-1) directly
      if (wave == 3) {
        #pragma unroll
        for (int r = 0; r < 4; ++r) {
          int prow = lhi * 4 + r;
          const float* pp = psumO + rg * 1024 + prow * 64 + llo * 4;
          union { unsigned long long u; float f[2]; } c0, c1;
          c0.u = ld64c(pp); c1.u = ld64c(pp + 2);
          float s = c0.f[0] + c0.f[1] + c1.f[0] + c1.f[1];
          s += __shfl_xor(s, 1, 16); s += __shfl_xor(s, 2, 16);
          s += __shfl_xor(s, 4, 16); s += __shfl_xor(s, 8, 16);
          int b2 = rg * 16 + prow;
          outp[(size_t)(t - 1) * BB * VV + (size_t)b2 * VV + cg * 16 + llo] = eo[r] / s;
        }
      }
    }
  }
}

// ---------------- host launcher ----------------

extern "C" void kernel_launch(void* const* d_in, const int* in_sizes, int n_in,
                              void* d_out, int out_size, void* d_ws, size_t ws_size,
                              hipStream_t stream) {
  (void)in_sizes; (void)n_in; (void)out_size; (void)ws_size;
  const float* enc    = (const float*)d_in[0];
  const float* hidden = (const float*)d_in[1];
  const float* dec0   = (const float*)d_in[2];
  const float* Wa     = (const float*)d_in[3];
  // d_in[4] = ba: unused (softmax shift-invariance)
  const float* v      = (const float*)d_in[5];
  const float* W_ih   = (const float*)d_in[6];
  const float* b_ih   = (const float*)d_in[7];
  const float* W_hh   = (const float*)d_in[8];
  const float* b_hh   = (const float*)d_in[9];
  const float* Wo     = (const float*)d_in[10];
  const float* bo     = (const float*)d_in[11];
  const float* Wf     = (const float*)d_in[12];
  const float* bfv    = (const float*)d_in[13];

  char* ws = (char*)d_ws;
  float* ve    = (float*)(ws + OFF_VE);
  float* es    = (float*)(ws + OFF_ES);
  float* attn  = (float*)(ws + OFF_A);
  float* ctx   = (float*)(ws + OFF_CTX);
  float* gictx = (float*)(ws + OFF_GICTX);
  float* oc    = (float*)(ws + OFF_OC);
  unsigned* flags = (unsigned*)(ws + OFF_FLAGS);
  float* psumB = (float*)(ws + OFF_PSUMB);
  float* psumO = (float*)(ws + OFF_PSUMO);
  short* e2    = (short*)(ws + OFF_E2);
  short* hb    = (short*)(ws + OFF_HB0);
  short* packW = (short*)(ws + OFF_PACKW);

  hipLaunchKernelGGL(K_init, dim3(256), dim3(256), 0, stream, hidden, dec0, hb, e2, flags);
  hipLaunchKernelGGL(K_ve, dim3(16), dim3(64), 0, stream, Wa, v, ve);
  hipLaunchKernelGGL(K_escore, dim3(LL * BB), dim3(64), 0, stream, enc, ve, es);
  hipLaunchKernelGGL(K_asm, dim3(BB), dim3(256), 0, stream, es, attn);
  hipLaunchKernelGGL(K_ctx, dim3(512), dim3(128), 0, stream, enc, attn, ctx);
  hipLaunchKernelGGL(K_gictx, dim3(4096), dim3(64), 0, stream, ctx, W_ih, b_ih, Wo, bo, gictx, oc);
  hipLaunchKernelGGL(K_pack, dim3(64 * 9 * 32), dim3(64), 0, stream, W_ih, W_hh, Wo, Wf, packW);
  hipLaunchKernelGGL(K_step, dim3(256), dim3(256), 0, stream,
                     (const bf16x8*)packW, e2, hb, hidden, psumB, psumO,
                     gictx, oc, b_hh, bfv, (float*)d_out, flags);
}